// Round 7
// baseline (110.199 us; speedup 1.0000x reference)
//
#include <hip/hip_runtime.h>
#include <hip/hip_bf16.h>

// Segment-sum: out[v,:] = sum_{r: idx[r]==v} H[r,:]
// H: [N=625000, 128] f32, idx: [N] int32, out: [V=50000, 128] f32.
//
// Round 7: fixed-capacity binning + 8-deep gather (16 entries/iter/wave).
//  K1 scatter: int4-vectorized; pos = atomicAdd(&counts[v],1); bin row id.
//  K2 gather : one wave per bucket. Invariants (round-5 lesson): every
//              __shfl executes with all 64 lanes active; group/tail split is
//              wave-uniform (cnt is per-bucket); tail is masked-accumulate
//              with shfl index clamped to entry 0 (valid whenever any
//              iteration runs). Full groups (16 entries) are unmasked ->
//              8 independent 512B nontemporal loads in flight per half-wave.

#ifndef V_SEG
#define V_SEG 50000
#endif
#define CAP 64

typedef float f4 __attribute__((ext_vector_type(4)));

__global__ void scatter_kernel(const int* __restrict__ idx,
                               int* __restrict__ counts,
                               int* __restrict__ rowids, int n) {
    const int n4 = n >> 2;                     // 625000 / 4 = 156250 exactly
    int i = blockIdx.x * blockDim.x + threadIdx.x;
    const int stride = gridDim.x * blockDim.x;
    const int4* __restrict__ idx4 = reinterpret_cast<const int4*>(idx);
    for (; i < n4; i += stride) {
        const int4 v = idx4[i];
        const int base = i << 2;
        int p;
        p = atomicAdd(&counts[v.x], 1); if (p < CAP) rowids[v.x * CAP + p] = base + 0;
        p = atomicAdd(&counts[v.y], 1); if (p < CAP) rowids[v.y * CAP + p] = base + 1;
        p = atomicAdd(&counts[v.z], 1); if (p < CAP) rowids[v.z * CAP + p] = base + 2;
        p = atomicAdd(&counts[v.w], 1); if (p < CAP) rowids[v.w * CAP + p] = base + 3;
    }
    // tail (n not multiple of 4)
    if (blockIdx.x == 0 && threadIdx.x < (n & 3)) {
        const int r = (n4 << 2) + threadIdx.x;
        const int v = idx[r];
        const int p = atomicAdd(&counts[v], 1);
        if (p < CAP) rowids[v * CAP + p] = r;
    }
}

__device__ __forceinline__ f4 nt_load_row(const float* H, int row, int l32) {
    return __builtin_nontemporal_load(
        reinterpret_cast<const f4*>(H + (size_t)row * 128) + l32);
}

__global__ __launch_bounds__(256) void gather_kernel(const float* __restrict__ H,
                                                     const int* __restrict__ counts,
                                                     const int* __restrict__ rowids,
                                                     const int* __restrict__ idx,
                                                     float* __restrict__ out,
                                                     int V, int n) {
    const int wid = blockIdx.x * (blockDim.x >> 6) + (threadIdx.x >> 6);
    if (wid >= V) return;
    const int lane = threadIdx.x & 63;
    const int half = lane >> 5;       // 0: even bucket entries, 1: odd
    const int l32  = lane & 31;       // float4 slot within the 128-col row

    const int cnt = counts[wid];      // wave-uniform
    f4 acc0 = {0.f, 0.f, 0.f, 0.f};
    f4 acc1 = {0.f, 0.f, 0.f, 0.f};
    f4 acc2 = {0.f, 0.f, 0.f, 0.f};
    f4 acc3 = {0.f, 0.f, 0.f, 0.f};
    f4 acc4 = {0.f, 0.f, 0.f, 0.f};
    f4 acc5 = {0.f, 0.f, 0.f, 0.f};
    f4 acc6 = {0.f, 0.f, 0.f, 0.f};
    f4 acc7 = {0.f, 0.f, 0.f, 0.f};

    if (cnt <= CAP) {
        // One coalesced load: lane i holds candidate rowid i of this bucket.
        const int rid = rowids[wid * CAP + lane];
        const int full = cnt >> 4;            // full 16-entry groups (uniform)
        int r = half;                         // this half covers entries r+2j
        for (int t = 0; t < full; ++t, r += 16) {
            // Unmasked: all 16 entries of this group are valid.
            int  row0 = __shfl(rid, r +  0, 64);
            int  row1 = __shfl(rid, r +  2, 64);
            int  row2 = __shfl(rid, r +  4, 64);
            int  row3 = __shfl(rid, r +  6, 64);
            int  row4 = __shfl(rid, r +  8, 64);
            int  row5 = __shfl(rid, r + 10, 64);
            int  row6 = __shfl(rid, r + 12, 64);
            int  row7 = __shfl(rid, r + 14, 64);
            f4 v0 = nt_load_row(H, row0, l32);
            f4 v1 = nt_load_row(H, row1, l32);
            f4 v2 = nt_load_row(H, row2, l32);
            f4 v3 = nt_load_row(H, row3, l32);
            f4 v4 = nt_load_row(H, row4, l32);
            f4 v5 = nt_load_row(H, row5, l32);
            f4 v6 = nt_load_row(H, row6, l32);
            f4 v7 = nt_load_row(H, row7, l32);
            acc0 += v0; acc1 += v1; acc2 += v2; acc3 += v3;
            acc4 += v4; acc5 += v5; acc6 += v6; acc7 += v7;
        }
        if ((full << 4) < cnt) {              // wave-uniform tail guard
            // Masked tail: clamp shfl index to entry 0 (valid: cnt > 0 here),
            // zero the accumulate. All 64 lanes active for every __shfl.
            const int r0 = r,     r1 = r + 2, r2 = r +  4, r3 = r +  6;
            const int r4 = r + 8, r5 = r +10, r6 = r + 12, r7 = r + 14;
            const int   i0 = (r0 < cnt) ? r0 : 0, i1 = (r1 < cnt) ? r1 : 0;
            const int   i2 = (r2 < cnt) ? r2 : 0, i3 = (r3 < cnt) ? r3 : 0;
            const int   i4 = (r4 < cnt) ? r4 : 0, i5 = (r5 < cnt) ? r5 : 0;
            const int   i6 = (r6 < cnt) ? r6 : 0, i7 = (r7 < cnt) ? r7 : 0;
            const float m0 = (r0 < cnt) ? 1.f : 0.f, m1 = (r1 < cnt) ? 1.f : 0.f;
            const float m2 = (r2 < cnt) ? 1.f : 0.f, m3 = (r3 < cnt) ? 1.f : 0.f;
            const float m4 = (r4 < cnt) ? 1.f : 0.f, m5 = (r5 < cnt) ? 1.f : 0.f;
            const float m6 = (r6 < cnt) ? 1.f : 0.f, m7 = (r7 < cnt) ? 1.f : 0.f;
            int  row0 = __shfl(rid, i0, 64), row1 = __shfl(rid, i1, 64);
            int  row2 = __shfl(rid, i2, 64), row3 = __shfl(rid, i3, 64);
            int  row4 = __shfl(rid, i4, 64), row5 = __shfl(rid, i5, 64);
            int  row6 = __shfl(rid, i6, 64), row7 = __shfl(rid, i7, 64);
            f4 v0 = nt_load_row(H, row0, l32);
            f4 v1 = nt_load_row(H, row1, l32);
            f4 v2 = nt_load_row(H, row2, l32);
            f4 v3 = nt_load_row(H, row3, l32);
            f4 v4 = nt_load_row(H, row4, l32);
            f4 v5 = nt_load_row(H, row5, l32);
            f4 v6 = nt_load_row(H, row6, l32);
            f4 v7 = nt_load_row(H, row7, l32);
            acc0 += m0 * v0; acc1 += m1 * v1; acc2 += m2 * v2; acc3 += m3 * v3;
            acc4 += m4 * v4; acc5 += m5 * v5; acc6 += m6 * v6; acc7 += m7 * v7;
        }
    } else {
        // Overflow fallback: full scan (correct for any input; effectively
        // never taken for Poisson(12.5) buckets). No cross-lane ops inside.
        for (int r = half; r < n; r += 2) {
            if (idx[r] == wid) {
                const f4 v = reinterpret_cast<const f4*>(H + (size_t)r * 128)[l32];
                acc0 += v;
            }
        }
    }

    f4 acc = ((acc0 + acc1) + (acc2 + acc3)) + ((acc4 + acc5) + (acc6 + acc7));

    // combine the two 32-lane halves (same columns, different row subsets)
    acc.x += __shfl_xor(acc.x, 32, 64);
    acc.y += __shfl_xor(acc.y, 32, 64);
    acc.z += __shfl_xor(acc.z, 32, 64);
    acc.w += __shfl_xor(acc.w, 32, 64);
    if (half == 0)
        __builtin_nontemporal_store(acc,
            reinterpret_cast<f4*>(out + (size_t)wid * 128) + l32);
}

// ---- fallback (if ws too small): direct f32 atomics ----
__global__ void atomic_fallback_kernel(const float* __restrict__ H,
                                       const int* __restrict__ idx,
                                       float* __restrict__ out, int n) {
    const int gid  = blockIdx.x * blockDim.x + threadIdx.x;
    const int row  = gid >> 5;
    const int lane = gid & 31;
    if (row >= n) return;
    const int v = idx[row];
    const float4 val = reinterpret_cast<const float4*>(H + (size_t)row * 128)[lane];
    float* dst = out + (size_t)v * 128 + (size_t)lane * 4;
    atomicAdd(dst + 0, val.x);
    atomicAdd(dst + 1, val.y);
    atomicAdd(dst + 2, val.z);
    atomicAdd(dst + 3, val.w);
}

static inline size_t align_up(size_t x, size_t a) { return (x + a - 1) & ~(a - 1); }

extern "C" void kernel_launch(void* const* d_in, const int* in_sizes, int n_in,
                              void* d_out, int out_size, void* d_ws, size_t ws_size,
                              hipStream_t stream) {
    const float* H   = (const float*)d_in[0];
    const int*   idx = (const int*)d_in[1];
    float*       out = (float*)d_out;
    const int n = in_sizes[1];          // 625000 rows
    const int V = V_SEG;

    // ws layout
    size_t o = 0;
    const size_t counts_off = o; o = align_up(o + (size_t)V * 4, 256);
    const size_t rowids_off = o; o = align_up(o + (size_t)V * CAP * 4, 256);
    const size_t need = o;

    if (ws_size < need) {
        (void)hipMemsetAsync(d_out, 0, (size_t)out_size * sizeof(float), stream);
        const int threads = 256;
        const int blocks = (n * 32 + threads - 1) / threads;
        atomic_fallback_kernel<<<blocks, threads, 0, stream>>>(H, idx, out, n);
        return;
    }

    char* ws = (char*)d_ws;
    int* counts = (int*)(ws + counts_off);
    int* rowids = (int*)(ws + rowids_off);

    (void)hipMemsetAsync(counts, 0, (size_t)V * 4, stream);

    scatter_kernel<<<1024, 256, 0, stream>>>(idx, counts, rowids, n);

    const int waves_per_block = 256 / 64;                    // 4 buckets per block
    const int gblocks = (V + waves_per_block - 1) / waves_per_block;
    gather_kernel<<<gblocks, 256, 0, stream>>>(H, counts, rowids, idx, out, V, n);
}

// Round 8
// 103.083 us; speedup vs baseline: 1.0690x; 1.0690x over previous
//
#include <hip/hip_runtime.h>
#include <hip/hip_bf16.h>

// Segment-sum: out[v,:] = sum_{r: idx[r]==v} H[r,:]
// H: [N=625000, 128] f32, idx: [N] int32, out: [V=50000, 128] f32.
//
// Round 8: fixed-capacity binning + exact-trip-count gather.
//  K1 scatter: int4-vectorized; pos = atomicAdd(&counts[v],1); bin row id.
//  K2 gather : one wave per bucket. steps = ceil(cnt/2) is wave-uniform ->
//              switch to a template<K> body with exactly K wave-loads
//              (2 rows per load: half 0 = even entries, half 1 = odd).
//              Only the final step can have an invalid odd entry; it is
//              handled by clamping the shfl index + masking the accumulate
//              (all 64 lanes active at every __shfl -- round-5 lesson).
//              No duplicate/masked loads in full steps.

#ifndef V_SEG
#define V_SEG 50000
#endif
#define CAP 64

typedef float f4 __attribute__((ext_vector_type(4)));

__global__ void scatter_kernel(const int* __restrict__ idx,
                               int* __restrict__ counts,
                               int* __restrict__ rowids, int n) {
    const int n4 = n >> 2;                     // 625000 / 4 = 156250 exactly
    int i = blockIdx.x * blockDim.x + threadIdx.x;
    const int stride = gridDim.x * blockDim.x;
    const int4* __restrict__ idx4 = reinterpret_cast<const int4*>(idx);
    for (; i < n4; i += stride) {
        const int4 v = idx4[i];
        const int base = i << 2;
        int p;
        p = atomicAdd(&counts[v.x], 1); if (p < CAP) rowids[v.x * CAP + p] = base + 0;
        p = atomicAdd(&counts[v.y], 1); if (p < CAP) rowids[v.y * CAP + p] = base + 1;
        p = atomicAdd(&counts[v.z], 1); if (p < CAP) rowids[v.z * CAP + p] = base + 2;
        p = atomicAdd(&counts[v.w], 1); if (p < CAP) rowids[v.w * CAP + p] = base + 3;
    }
    // tail (n not multiple of 4)
    if (blockIdx.x == 0 && threadIdx.x < (n & 3)) {
        const int r = (n4 << 2) + threadIdx.x;
        const int v = idx[r];
        const int p = atomicAdd(&counts[v], 1);
        if (p < CAP) rowids[v * CAP + p] = r;
    }
}

__device__ __forceinline__ f4 nt_load_row(const float* __restrict__ H, int row, int l32) {
    return __builtin_nontemporal_load(
        reinterpret_cast<const f4*>(H + (size_t)row * 128) + l32);
}

// Exactly K wave-loads; entry e = 2t + half. For t < K-1 entries are always
// valid (steps == K implies cnt >= 2K-1). Final step masked per-lane.
template<int K>
__device__ __forceinline__ f4 gather_steps(const float* __restrict__ H,
                                           int rid, int cnt, int half, int l32) {
    f4 a0 = {0.f,0.f,0.f,0.f}, a1 = {0.f,0.f,0.f,0.f};
    f4 a2 = {0.f,0.f,0.f,0.f}, a3 = {0.f,0.f,0.f,0.f};
    int  rows[K];
    f4   vals[K];
#pragma unroll
    for (int t = 0; t < K; ++t) {
        const int e  = 2 * t + half;
        const int ec = (e < cnt) ? e : 0;       // only reachable masked: t==K-1
        rows[t] = __shfl(rid, ec, 64);          // all 64 lanes active
    }
#pragma unroll
    for (int t = 0; t < K; ++t)
        vals[t] = nt_load_row(H, rows[t], l32); // K independent 512B segments
#pragma unroll
    for (int t = 0; t < K; ++t) {
        const int   e = 2 * t + half;
        const float m = (e < cnt) ? 1.f : 0.f;
        const f4    v = m * vals[t];
        if ((t & 3) == 0) a0 += v;
        else if ((t & 3) == 1) a1 += v;
        else if ((t & 3) == 2) a2 += v;
        else a3 += v;
    }
    return (a0 + a1) + (a2 + a3);
}

__global__ __launch_bounds__(256) void gather_kernel(const float* __restrict__ H,
                                                     const int* __restrict__ counts,
                                                     const int* __restrict__ rowids,
                                                     const int* __restrict__ idx,
                                                     float* __restrict__ out,
                                                     int V, int n) {
    const int wid = blockIdx.x * (blockDim.x >> 6) + (threadIdx.x >> 6);
    if (wid >= V) return;
    const int lane = threadIdx.x & 63;
    const int half = lane >> 5;       // 0: even bucket entries, 1: odd
    const int l32  = lane & 31;       // float4 slot within the 128-col row

    const int cnt = counts[wid];      // wave-uniform
    f4 acc = {0.f, 0.f, 0.f, 0.f};

    if (cnt <= CAP) {
        // One coalesced load: lane i holds candidate rowid i of this bucket.
        const int rid = rowids[wid * CAP + lane];
        const int steps = (cnt + 1) >> 1;       // wave-uniform
        switch (steps) {                        // wave-uniform branch
            case 0: break;                      // empty bucket -> zeros
            case 1:  acc = gather_steps<1>(H, rid, cnt, half, l32);  break;
            case 2:  acc = gather_steps<2>(H, rid, cnt, half, l32);  break;
            case 3:  acc = gather_steps<3>(H, rid, cnt, half, l32);  break;
            case 4:  acc = gather_steps<4>(H, rid, cnt, half, l32);  break;
            case 5:  acc = gather_steps<5>(H, rid, cnt, half, l32);  break;
            case 6:  acc = gather_steps<6>(H, rid, cnt, half, l32);  break;
            case 7:  acc = gather_steps<7>(H, rid, cnt, half, l32);  break;
            case 8:  acc = gather_steps<8>(H, rid, cnt, half, l32);  break;
            case 9:  acc = gather_steps<9>(H, rid, cnt, half, l32);  break;
            case 10: acc = gather_steps<10>(H, rid, cnt, half, l32); break;
            case 11: acc = gather_steps<11>(H, rid, cnt, half, l32); break;
            case 12: acc = gather_steps<12>(H, rid, cnt, half, l32); break;
            case 13: acc = gather_steps<13>(H, rid, cnt, half, l32); break;
            case 14: acc = gather_steps<14>(H, rid, cnt, half, l32); break;
            case 15: acc = gather_steps<15>(H, rid, cnt, half, l32); break;
            case 16: acc = gather_steps<16>(H, rid, cnt, half, l32); break;
            default: {
                // 32 < cnt <= CAP: generic 4-deep masked loop (rare).
                f4 b0 = {0.f,0.f,0.f,0.f}, b1 = {0.f,0.f,0.f,0.f};
                f4 b2 = {0.f,0.f,0.f,0.f}, b3 = {0.f,0.f,0.f,0.f};
                const int iters = (cnt + 7) >> 3;   // wave-uniform
                int r = half;
                for (int t = 0; t < iters; ++t, r += 8) {
                    const int r0 = r, r1 = r + 2, r2 = r + 4, r3 = r + 6;
                    const int   i0 = (r0 < cnt) ? r0 : 0, i1 = (r1 < cnt) ? r1 : 0;
                    const int   i2 = (r2 < cnt) ? r2 : 0, i3 = (r3 < cnt) ? r3 : 0;
                    const float m0 = (r0 < cnt) ? 1.f : 0.f, m1 = (r1 < cnt) ? 1.f : 0.f;
                    const float m2 = (r2 < cnt) ? 1.f : 0.f, m3 = (r3 < cnt) ? 1.f : 0.f;
                    const int row0 = __shfl(rid, i0, 64);
                    const int row1 = __shfl(rid, i1, 64);
                    const int row2 = __shfl(rid, i2, 64);
                    const int row3 = __shfl(rid, i3, 64);
                    b0 += m0 * nt_load_row(H, row0, l32);
                    b1 += m1 * nt_load_row(H, row1, l32);
                    b2 += m2 * nt_load_row(H, row2, l32);
                    b3 += m3 * nt_load_row(H, row3, l32);
                }
                acc = (b0 + b1) + (b2 + b3);
            } break;
        }
    } else {
        // Overflow fallback: full scan (correct for any input; effectively
        // never taken for Poisson(12.5) buckets). No cross-lane ops inside.
        for (int r = half; r < n; r += 2) {
            if (idx[r] == wid) {
                acc += reinterpret_cast<const f4*>(H + (size_t)r * 128)[l32];
            }
        }
    }

    // combine the two 32-lane halves (same columns, different row subsets)
    acc.x += __shfl_xor(acc.x, 32, 64);
    acc.y += __shfl_xor(acc.y, 32, 64);
    acc.z += __shfl_xor(acc.z, 32, 64);
    acc.w += __shfl_xor(acc.w, 32, 64);
    if (half == 0)
        __builtin_nontemporal_store(acc,
            reinterpret_cast<f4*>(out + (size_t)wid * 128) + l32);
}

// ---- fallback (if ws too small): direct f32 atomics ----
__global__ void atomic_fallback_kernel(const float* __restrict__ H,
                                       const int* __restrict__ idx,
                                       float* __restrict__ out, int n) {
    const int gid  = blockIdx.x * blockDim.x + threadIdx.x;
    const int row  = gid >> 5;
    const int lane = gid & 31;
    if (row >= n) return;
    const int v = idx[row];
    const float4 val = reinterpret_cast<const float4*>(H + (size_t)row * 128)[lane];
    float* dst = out + (size_t)v * 128 + (size_t)lane * 4;
    atomicAdd(dst + 0, val.x);
    atomicAdd(dst + 1, val.y);
    atomicAdd(dst + 2, val.z);
    atomicAdd(dst + 3, val.w);
}

static inline size_t align_up(size_t x, size_t a) { return (x + a - 1) & ~(a - 1); }

extern "C" void kernel_launch(void* const* d_in, const int* in_sizes, int n_in,
                              void* d_out, int out_size, void* d_ws, size_t ws_size,
                              hipStream_t stream) {
    const float* H   = (const float*)d_in[0];
    const int*   idx = (const int*)d_in[1];
    float*       out = (float*)d_out;
    const int n = in_sizes[1];          // 625000 rows
    const int V = V_SEG;

    // ws layout
    size_t o = 0;
    const size_t counts_off = o; o = align_up(o + (size_t)V * 4, 256);
    const size_t rowids_off = o; o = align_up(o + (size_t)V * CAP * 4, 256);
    const size_t need = o;

    if (ws_size < need) {
        (void)hipMemsetAsync(d_out, 0, (size_t)out_size * sizeof(float), stream);
        const int threads = 256;
        const int blocks = (n * 32 + threads - 1) / threads;
        atomic_fallback_kernel<<<blocks, threads, 0, stream>>>(H, idx, out, n);
        return;
    }

    char* ws = (char*)d_ws;
    int* counts = (int*)(ws + counts_off);
    int* rowids = (int*)(ws + rowids_off);

    (void)hipMemsetAsync(counts, 0, (size_t)V * 4, stream);

    scatter_kernel<<<1024, 256, 0, stream>>>(idx, counts, rowids, n);

    const int waves_per_block = 256 / 64;                    // 4 buckets per block
    const int gblocks = (V + waves_per_block - 1) / waves_per_block;
    gather_kernel<<<gblocks, 256, 0, stream>>>(H, counts, rowids, idx, out, V, n);
}

// Round 9
// 102.715 us; speedup vs baseline: 1.0729x; 1.0036x over previous
//
#include <hip/hip_runtime.h>
#include <hip/hip_bf16.h>

// Segment-sum: out[v,:] = sum_{r: idx[r]==v} H[r,:]
// H: [N=625000, 128] f32, idx: [N] int32, out: [V=50000, 128] f32.
//
// Round 9: fixed-capacity binning + exact-trip-count gather + predicated
// rowid load.
//  K1 scatter: int4-vectorized, exact grid; pos = atomicAdd(&counts[v],1).
//  K2 gather : one wave per bucket. steps = ceil(cnt/2) is wave-uniform ->
//              switch to template<K> body with exactly K wave-loads (2 rows
//              per load: half 0 = even entries, half 1 = odd). rowid load is
//              predicated on lane < cnt (1 cache line for typical cnt~12
//              instead of 4); lanes reconverge before any __shfl and every
//              shfl index is < cnt (round-5 invariants preserved).

#ifndef V_SEG
#define V_SEG 50000
#endif
#define CAP 64

typedef float f4 __attribute__((ext_vector_type(4)));

__global__ void scatter_kernel(const int* __restrict__ idx,
                               int* __restrict__ counts,
                               int* __restrict__ rowids, int n) {
    const int n4 = n >> 2;                     // 625000 / 4 = 156250 exactly
    int i = blockIdx.x * blockDim.x + threadIdx.x;
    const int stride = gridDim.x * blockDim.x;
    const int4* __restrict__ idx4 = reinterpret_cast<const int4*>(idx);
    for (; i < n4; i += stride) {
        const int4 v = idx4[i];
        const int base = i << 2;
        int p;
        p = atomicAdd(&counts[v.x], 1); if (p < CAP) rowids[v.x * CAP + p] = base + 0;
        p = atomicAdd(&counts[v.y], 1); if (p < CAP) rowids[v.y * CAP + p] = base + 1;
        p = atomicAdd(&counts[v.z], 1); if (p < CAP) rowids[v.z * CAP + p] = base + 2;
        p = atomicAdd(&counts[v.w], 1); if (p < CAP) rowids[v.w * CAP + p] = base + 3;
    }
    // tail (n not multiple of 4)
    if (blockIdx.x == 0 && threadIdx.x < (n & 3)) {
        const int r = (n4 << 2) + threadIdx.x;
        const int v = idx[r];
        const int p = atomicAdd(&counts[v], 1);
        if (p < CAP) rowids[v * CAP + p] = r;
    }
}

__device__ __forceinline__ f4 nt_load_row(const float* __restrict__ H, int row, int l32) {
    return __builtin_nontemporal_load(
        reinterpret_cast<const f4*>(H + (size_t)row * 128) + l32);
}

// Exactly K wave-loads; entry e = 2t + half. For t < K-1 entries are always
// valid (steps == K implies cnt >= 2K-1). Final step masked per-lane.
template<int K>
__device__ __forceinline__ f4 gather_steps(const float* __restrict__ H,
                                           int rid, int cnt, int half, int l32) {
    f4 a0 = {0.f,0.f,0.f,0.f}, a1 = {0.f,0.f,0.f,0.f};
    f4 a2 = {0.f,0.f,0.f,0.f}, a3 = {0.f,0.f,0.f,0.f};
    int  rows[K];
    f4   vals[K];
#pragma unroll
    for (int t = 0; t < K; ++t) {
        const int e  = 2 * t + half;
        const int ec = (e < cnt) ? e : 0;       // only reachable masked: t==K-1
        rows[t] = __shfl(rid, ec, 64);          // all 64 lanes active
    }
#pragma unroll
    for (int t = 0; t < K; ++t)
        vals[t] = nt_load_row(H, rows[t], l32); // K independent 512B segments
#pragma unroll
    for (int t = 0; t < K; ++t) {
        const int   e = 2 * t + half;
        const float m = (e < cnt) ? 1.f : 0.f;
        const f4    v = m * vals[t];
        if ((t & 3) == 0) a0 += v;
        else if ((t & 3) == 1) a1 += v;
        else if ((t & 3) == 2) a2 += v;
        else a3 += v;
    }
    return (a0 + a1) + (a2 + a3);
}

__global__ __launch_bounds__(256) void gather_kernel(const float* __restrict__ H,
                                                     const int* __restrict__ counts,
                                                     const int* __restrict__ rowids,
                                                     const int* __restrict__ idx,
                                                     float* __restrict__ out,
                                                     int V, int n) {
    const int wid = blockIdx.x * (blockDim.x >> 6) + (threadIdx.x >> 6);
    if (wid >= V) return;
    const int lane = threadIdx.x & 63;
    const int half = lane >> 5;       // 0: even bucket entries, 1: odd
    const int l32  = lane & 31;       // float4 slot within the 128-col row

    const int cnt = counts[wid];      // wave-uniform
    f4 acc = {0.f, 0.f, 0.f, 0.f};

    if (cnt <= CAP) {
        // Predicated coalesced load: only the lanes whose rowid can be
        // consumed by a shfl (index < cnt) load. Typical cnt~12 -> 1 cache
        // line instead of 4. Lanes reconverge before the shfls below.
        int rid = 0;
        if (lane < cnt) rid = rowids[wid * CAP + lane];
        const int steps = (cnt + 1) >> 1;       // wave-uniform
        switch (steps) {                        // wave-uniform branch
            case 0: break;                      // empty bucket -> zeros
            case 1:  acc = gather_steps<1>(H, rid, cnt, half, l32);  break;
            case 2:  acc = gather_steps<2>(H, rid, cnt, half, l32);  break;
            case 3:  acc = gather_steps<3>(H, rid, cnt, half, l32);  break;
            case 4:  acc = gather_steps<4>(H, rid, cnt, half, l32);  break;
            case 5:  acc = gather_steps<5>(H, rid, cnt, half, l32);  break;
            case 6:  acc = gather_steps<6>(H, rid, cnt, half, l32);  break;
            case 7:  acc = gather_steps<7>(H, rid, cnt, half, l32);  break;
            case 8:  acc = gather_steps<8>(H, rid, cnt, half, l32);  break;
            case 9:  acc = gather_steps<9>(H, rid, cnt, half, l32);  break;
            case 10: acc = gather_steps<10>(H, rid, cnt, half, l32); break;
            case 11: acc = gather_steps<11>(H, rid, cnt, half, l32); break;
            case 12: acc = gather_steps<12>(H, rid, cnt, half, l32); break;
            case 13: acc = gather_steps<13>(H, rid, cnt, half, l32); break;
            case 14: acc = gather_steps<14>(H, rid, cnt, half, l32); break;
            case 15: acc = gather_steps<15>(H, rid, cnt, half, l32); break;
            case 16: acc = gather_steps<16>(H, rid, cnt, half, l32); break;
            default: {
                // 32 < cnt <= CAP: generic 4-deep masked loop (rare).
                f4 b0 = {0.f,0.f,0.f,0.f}, b1 = {0.f,0.f,0.f,0.f};
                f4 b2 = {0.f,0.f,0.f,0.f}, b3 = {0.f,0.f,0.f,0.f};
                const int iters = (cnt + 7) >> 3;   // wave-uniform
                int r = half;
                for (int t = 0; t < iters; ++t, r += 8) {
                    const int r0 = r, r1 = r + 2, r2 = r + 4, r3 = r + 6;
                    const int   i0 = (r0 < cnt) ? r0 : 0, i1 = (r1 < cnt) ? r1 : 0;
                    const int   i2 = (r2 < cnt) ? r2 : 0, i3 = (r3 < cnt) ? r3 : 0;
                    const float m0 = (r0 < cnt) ? 1.f : 0.f, m1 = (r1 < cnt) ? 1.f : 0.f;
                    const float m2 = (r2 < cnt) ? 1.f : 0.f, m3 = (r3 < cnt) ? 1.f : 0.f;
                    const int row0 = __shfl(rid, i0, 64);
                    const int row1 = __shfl(rid, i1, 64);
                    const int row2 = __shfl(rid, i2, 64);
                    const int row3 = __shfl(rid, i3, 64);
                    b0 += m0 * nt_load_row(H, row0, l32);
                    b1 += m1 * nt_load_row(H, row1, l32);
                    b2 += m2 * nt_load_row(H, row2, l32);
                    b3 += m3 * nt_load_row(H, row3, l32);
                }
                acc = (b0 + b1) + (b2 + b3);
            } break;
        }
    } else {
        // Overflow fallback: full scan (correct for any input; effectively
        // never taken for Poisson(12.5) buckets). No cross-lane ops inside.
        for (int r = half; r < n; r += 2) {
            if (idx[r] == wid) {
                acc += reinterpret_cast<const f4*>(H + (size_t)r * 128)[l32];
            }
        }
    }

    // combine the two 32-lane halves (same columns, different row subsets)
    acc.x += __shfl_xor(acc.x, 32, 64);
    acc.y += __shfl_xor(acc.y, 32, 64);
    acc.z += __shfl_xor(acc.z, 32, 64);
    acc.w += __shfl_xor(acc.w, 32, 64);
    if (half == 0)
        __builtin_nontemporal_store(acc,
            reinterpret_cast<f4*>(out + (size_t)wid * 128) + l32);
}

// ---- fallback (if ws too small): direct f32 atomics ----
__global__ void atomic_fallback_kernel(const float* __restrict__ H,
                                       const int* __restrict__ idx,
                                       float* __restrict__ out, int n) {
    const int gid  = blockIdx.x * blockDim.x + threadIdx.x;
    const int row  = gid >> 5;
    const int lane = gid & 31;
    if (row >= n) return;
    const int v = idx[row];
    const float4 val = reinterpret_cast<const float4*>(H + (size_t)row * 128)[lane];
    float* dst = out + (size_t)v * 128 + (size_t)lane * 4;
    atomicAdd(dst + 0, val.x);
    atomicAdd(dst + 1, val.y);
    atomicAdd(dst + 2, val.z);
    atomicAdd(dst + 3, val.w);
}

static inline size_t align_up(size_t x, size_t a) { return (x + a - 1) & ~(a - 1); }

extern "C" void kernel_launch(void* const* d_in, const int* in_sizes, int n_in,
                              void* d_out, int out_size, void* d_ws, size_t ws_size,
                              hipStream_t stream) {
    const float* H   = (const float*)d_in[0];
    const int*   idx = (const int*)d_in[1];
    float*       out = (float*)d_out;
    const int n = in_sizes[1];          // 625000 rows
    const int V = V_SEG;

    // ws layout
    size_t o = 0;
    const size_t counts_off = o; o = align_up(o + (size_t)V * 4, 256);
    const size_t rowids_off = o; o = align_up(o + (size_t)V * CAP * 4, 256);
    const size_t need = o;

    if (ws_size < need) {
        (void)hipMemsetAsync(d_out, 0, (size_t)out_size * sizeof(float), stream);
        const int threads = 256;
        const int blocks = (n * 32 + threads - 1) / threads;
        atomic_fallback_kernel<<<blocks, threads, 0, stream>>>(H, idx, out, n);
        return;
    }

    char* ws = (char*)d_ws;
    int* counts = (int*)(ws + counts_off);
    int* rowids = (int*)(ws + rowids_off);

    (void)hipMemsetAsync(counts, 0, (size_t)V * 4, stream);

    // exact grid: one int4 per thread (+ tail in block 0)
    const int n4 = n >> 2;
    const int sblocks = (n4 + 255) / 256;
    scatter_kernel<<<sblocks, 256, 0, stream>>>(idx, counts, rowids, n);

    const int waves_per_block = 256 / 64;                    // 4 buckets per block
    const int gblocks = (V + waves_per_block - 1) / waves_per_block;
    gather_kernel<<<gblocks, 256, 0, stream>>>(H, counts, rowids, idx, out, V, n);
}